// Round 1
// baseline (266.479 us; speedup 1.0000x reference)
//
#include <hip/hip_runtime.h>

// SSIM loss over [8,8,3,256,256] fp32: 192 planes of 256x256.
// Separable 11x11 Gaussian (sigma=1.5), zero ("same") padding, 5 channels
// (x, y, x^2, y^2, x*y), SSIM map, global mean, out = 1 - mean.

#define WSZ 11
#define RAD 5
#define TILE 32
#define IN_TILE 42            // TILE + 2*RAD
#define SX_STRIDE 43          // odd stride -> bank-conflict-free-ish
#define HB_STRIDE 33          // 32+1 -> breaks r*32 bank aliasing
#define IMH 256
#define IMW 256
#define NPLANES 192           // 8*8*3
#define NPIX (192LL * 256 * 256)

__global__ __launch_bounds__(256) void ssim_tile_kernel(
    const float* __restrict__ pred,
    const float* __restrict__ targ,
    float* __restrict__ accum)
{
    __shared__ float sx[IN_TILE][SX_STRIDE];
    __shared__ float sy[IN_TILE][SX_STRIDE];
    __shared__ float hb[5][IN_TILE][HB_STRIDE];
    __shared__ float wsum[4];

    const int tid = threadIdx.x;
    const int b = blockIdx.x;
    const int plane = b >> 6;          // 64 tiles per plane
    const int trem = b & 63;
    const int ty0 = (trem >> 3) << 5;  // tile row origin in image
    const int tx0 = (trem & 7) << 5;   // tile col origin

    // --- Gaussian weights (match reference: exp / (sum + 1e-12)) ---
    float w[WSZ];
    {
        float s = 0.f;
#pragma unroll
        for (int i = 0; i < WSZ; ++i) {
            float c = (float)(i - RAD);
            w[i] = expf(-(c * c) / (2.f * 1.5f * 1.5f));
            s += w[i];
        }
        float inv = 1.f / (s + 1e-12f);
#pragma unroll
        for (int i = 0; i < WSZ; ++i) w[i] *= inv;
    }

    // --- Stage 1: load clipped x,y tile with halo (zero padding) ---
    const size_t pbase = (size_t)plane * (IMH * IMW);
    for (int i = tid; i < IN_TILE * IN_TILE; i += 256) {
        int r = i / IN_TILE;
        int c = i - r * IN_TILE;
        int gr = ty0 - RAD + r;
        int gc = tx0 - RAD + c;
        float vx = 0.f, vy = 0.f;
        if (gr >= 0 && gr < IMH && gc >= 0 && gc < IMW) {
            size_t gi = pbase + (size_t)gr * IMW + gc;
            vx = fminf(fmaxf(pred[gi], 0.f), 1.f);
            vy = fminf(fmaxf(targ[gi], 0.f), 1.f);
        }
        sx[r][c] = vx;
        sy[r][c] = vy;
    }
    __syncthreads();

    // --- Stage 2: horizontal pass. 42 rows x 4 segments of 8 output cols.
    // Sliding window: 18 input values produce 8 outputs. 5 channels on the fly.
    for (int item = tid; item < IN_TILE * 4; item += 256) {
        int r = item >> 2;
        int c0 = (item & 3) << 3;  // output col base: 0,8,16,24
        float xv[18], yv[18];
#pragma unroll
        for (int k = 0; k < 18; ++k) {
            xv[k] = sx[r][c0 + k];
            yv[k] = sy[r][c0 + k];
        }
#pragma unroll
        for (int j = 0; j < 8; ++j) {
            float ax = 0.f, ay = 0.f, axx = 0.f, ayy = 0.f, axy = 0.f;
#pragma unroll
            for (int k = 0; k < WSZ; ++k) {
                float xx = xv[j + k], yy = yv[j + k];
                float tx = w[k] * xx, ty = w[k] * yy;
                ax += tx; ay += ty;
                axx += tx * xx; ayy += ty * yy; axy += tx * yy;
            }
            hb[0][r][c0 + j] = ax;
            hb[1][r][c0 + j] = ay;
            hb[2][r][c0 + j] = axx;
            hb[3][r][c0 + j] = ayy;
            hb[4][r][c0 + j] = axy;
        }
    }
    __syncthreads();

    // --- Stage 3: vertical pass + SSIM. Thread = (col, 4 consecutive rows).
    const int c = tid & 31;
    const int r0 = (tid >> 5) << 2;  // 0,4,...,28
    float colv[5][14];
#pragma unroll
    for (int q = 0; q < 5; ++q)
#pragma unroll
        for (int k = 0; k < 14; ++k)
            colv[q][k] = hb[q][r0 + k][c];

    float lsum = 0.f;
    const float C1 = 1e-4f, C2 = 9e-4f;
#pragma unroll
    for (int j = 0; j < 4; ++j) {
        float mx = 0.f, my = 0.f, sxx = 0.f, syy = 0.f, sxy = 0.f;
#pragma unroll
        for (int k = 0; k < WSZ; ++k) {
            float wk = w[k];
            mx  += wk * colv[0][j + k];
            my  += wk * colv[1][j + k];
            sxx += wk * colv[2][j + k];
            syy += wk * colv[3][j + k];
            sxy += wk * colv[4][j + k];
        }
        float mx2 = mx * mx, my2 = my * my, mxy = mx * my;
        float vx = fmaxf(sxx - mx2, 0.f);
        float vy = fmaxf(syy - my2, 0.f);
        float vxy = sxy - mxy;
        float num = (2.f * mxy + C1) * (2.f * vxy + C2);
        float den = (mx2 + my2 + C1) * (vx + vy + C2);
        lsum += num / (den + 1e-8f);
    }

    // --- Stage 4: reduce. Wave shuffle (64 lanes) -> LDS -> one atomic. ---
#pragma unroll
    for (int off = 32; off > 0; off >>= 1)
        lsum += __shfl_down(lsum, off, 64);
    const int lane = tid & 63, wv = tid >> 6;
    if (lane == 0) wsum[wv] = lsum;
    __syncthreads();
    if (tid == 0) {
        float bs = wsum[0] + wsum[1] + wsum[2] + wsum[3];
        atomicAdd(accum, bs);
    }
}

__global__ void ssim_finalize(const float* __restrict__ accum,
                              float* __restrict__ out)
{
    out[0] = 1.0f - accum[0] / (float)NPIX;
}

extern "C" void kernel_launch(void* const* d_in, const int* in_sizes, int n_in,
                              void* d_out, int out_size, void* d_ws, size_t ws_size,
                              hipStream_t stream) {
    const float* pred = (const float*)d_in[0];
    const float* targ = (const float*)d_in[1];
    float* out = (float*)d_out;
    float* acc = (float*)d_ws;

    hipMemsetAsync(acc, 0, sizeof(float), stream);
    // 192 planes * 64 tiles = 12288 blocks
    ssim_tile_kernel<<<NPLANES * 64, 256, 0, stream>>>(pred, targ, acc);
    ssim_finalize<<<1, 1, 0, stream>>>(acc, out);
}

// Round 2
// 190.693 us; speedup vs baseline: 1.3974x; 1.3974x over previous
//
#include <hip/hip_runtime.h>

// SSIM loss over [8,8,3,256,256] fp32.
// Wave-autonomous design: one 64-lane wave owns an 8-row band of one
// 256x256 plane. Each lane owns 4 consecutive columns (float4 loads).
// Vertical 11-tap Gaussian via register ring buffer (11 rows x {x,y} x 4).
// Horizontal 11-tap via cross-lane __shfl (no LDS, no barriers).
// 5 channels (x, y, x^2, y^2, x*y), SSIM map, atomic-spread reduction.

#define WSZ 11
#define RAD 5
#define IMH 256
#define IMW 256
#define BAND 8
#define NBANDS (IMH / BAND)     // 32
#define NPLANES 192             // 8*8*3
#define NPIXF (192.0f * 256.0f * 256.0f)
#define NSLOTS 256

__device__ __forceinline__ float clip01(float v) {
    return fminf(fmaxf(v, 0.f), 1.f);
}

__global__ __launch_bounds__(64) void ssim_band_kernel(
    const float* __restrict__ pred,
    const float* __restrict__ targ,
    float* __restrict__ accum)
{
    const int lane = threadIdx.x;          // 0..63, one wave per block
    const int b = blockIdx.x;
    const int plane = b >> 5;              // 32 bands per plane
    const int band = b & 31;
    const int r0 = band * BAND;

    const float4* __restrict__ pp =
        (const float4*)(pred + (size_t)plane * (IMH * IMW));
    const float4* __restrict__ tp =
        (const float4*)(targ + (size_t)plane * (IMH * IMW));

    // Gaussian weights (match reference: exp / (sum + 1e-12))
    float w[WSZ];
    {
        float s = 0.f;
#pragma unroll
        for (int i = 0; i < WSZ; ++i) {
            float c = (float)(i - RAD);
            w[i] = expf(-(c * c) / (2.f * 1.5f * 1.5f));
            s += w[i];
        }
        float inv = 1.f / (s + 1e-12f);
#pragma unroll
        for (int i = 0; i < WSZ; ++i) w[i] *= inv;
    }

    // Register ring: rows r-5..r+5, clipped x and y, 4 cols per lane.
    float X[WSZ][4], Y[WSZ][4];

    // Preload rows r0-5 .. r0+4 into slots 0..9 (zero pad above image).
#pragma unroll
    for (int j = 0; j < 10; ++j) {
        const int r = r0 - RAD + j;        // max r0+4 = 252 < 256 always
        float4 a = make_float4(0.f, 0.f, 0.f, 0.f);
        float4 c = a;
        if (r >= 0) { a = pp[r * 64 + lane]; c = tp[r * 64 + lane]; }
        X[j][0] = clip01(a.x); X[j][1] = clip01(a.y);
        X[j][2] = clip01(a.z); X[j][3] = clip01(a.w);
        Y[j][0] = clip01(c.x); Y[j][1] = clip01(c.y);
        Y[j][2] = clip01(c.z); Y[j][3] = clip01(c.w);
    }

    const float C1 = 1e-4f, C2 = 9e-4f;
    float lsum = 0.f;

#pragma unroll 1
    for (int i = 0; i < BAND; ++i) {
        // Load newest row (r0+5+i) into slot 10 (zero pad below image).
        {
            const int r = r0 + RAD + i;
            float4 a = make_float4(0.f, 0.f, 0.f, 0.f);
            float4 c = a;
            if (r < IMH) { a = pp[r * 64 + lane]; c = tp[r * 64 + lane]; }
            X[10][0] = clip01(a.x); X[10][1] = clip01(a.y);
            X[10][2] = clip01(a.z); X[10][3] = clip01(a.w);
            Y[10][0] = clip01(c.x); Y[10][1] = clip01(c.y);
            Y[10][2] = clip01(c.z); Y[10][3] = clip01(c.w);
        }

        // Vertical pass: 5 channels x 4 cols.
        float vd[5][4];
#pragma unroll
        for (int j = 0; j < 4; ++j) {
            vd[0][j] = 0.f; vd[1][j] = 0.f; vd[2][j] = 0.f;
            vd[3][j] = 0.f; vd[4][j] = 0.f;
        }
#pragma unroll
        for (int k = 0; k < WSZ; ++k) {
            const float wk = w[k];
#pragma unroll
            for (int j = 0; j < 4; ++j) {
                const float x = X[k][j], y = Y[k][j];
                const float wx = wk * x, wy = wk * y;
                vd[0][j] += wx;
                vd[1][j] += wy;
                vd[2][j] = fmaf(wx, x, vd[2][j]);
                vd[3][j] = fmaf(wy, y, vd[3][j]);
                vd[4][j] = fmaf(wx, y, vd[4][j]);
            }
        }

        // Horizontal pass per channel via shuffles.
        // Window covers cols c0-5..c0+8 (14 values) -> 4 outputs.
        float hf[5][4];
#pragma unroll
        for (int ch = 0; ch < 5; ++ch) {
            float wnd[14];
            wnd[5] = vd[ch][0]; wnd[6] = vd[ch][1];
            wnd[7] = vd[ch][2]; wnd[8] = vd[ch][3];
            wnd[1] = __shfl_up(vd[ch][0], 1, 64);
            wnd[2] = __shfl_up(vd[ch][1], 1, 64);
            wnd[3] = __shfl_up(vd[ch][2], 1, 64);
            wnd[4] = __shfl_up(vd[ch][3], 1, 64);
            wnd[0] = __shfl_up(vd[ch][3], 2, 64);
            wnd[9]  = __shfl_down(vd[ch][0], 1, 64);
            wnd[10] = __shfl_down(vd[ch][1], 1, 64);
            wnd[11] = __shfl_down(vd[ch][2], 1, 64);
            wnd[12] = __shfl_down(vd[ch][3], 1, 64);
            wnd[13] = __shfl_down(vd[ch][0], 2, 64);
            // zero padding at image edges
            if (lane == 0) {
                wnd[0] = 0.f; wnd[1] = 0.f; wnd[2] = 0.f;
                wnd[3] = 0.f; wnd[4] = 0.f;
            } else if (lane == 1) {
                wnd[0] = 0.f;
            }
            if (lane == 63) {
                wnd[9] = 0.f; wnd[10] = 0.f; wnd[11] = 0.f;
                wnd[12] = 0.f; wnd[13] = 0.f;
            } else if (lane == 62) {
                wnd[13] = 0.f;
            }
#pragma unroll
            for (int j = 0; j < 4; ++j) {
                float a = 0.f;
#pragma unroll
                for (int k = 0; k < WSZ; ++k)
                    a = fmaf(w[k], wnd[j + k], a);
                hf[ch][j] = a;
            }
        }

        // SSIM for 4 pixels.
#pragma unroll
        for (int j = 0; j < 4; ++j) {
            const float mx = hf[0][j], my = hf[1][j];
            const float mx2 = mx * mx, my2 = my * my, mxy = mx * my;
            const float vx = fmaxf(hf[2][j] - mx2, 0.f);
            const float vy = fmaxf(hf[3][j] - my2, 0.f);
            const float vxy = hf[4][j] - mxy;
            const float num = (2.f * mxy + C1) * (2.f * vxy + C2);
            const float den = (mx2 + my2 + C1) * (vx + vy + C2) + 1e-8f;
            lsum += num * __builtin_amdgcn_rcpf(den);
        }

        // Shift ring down by one row.
#pragma unroll
        for (int k = 0; k < 10; ++k) {
#pragma unroll
            for (int j = 0; j < 4; ++j) {
                X[k][j] = X[k + 1][j];
                Y[k][j] = Y[k + 1][j];
            }
        }
    }

    // Wave reduction (64 lanes), one atomic per wave into spread slots.
#pragma unroll
    for (int off = 32; off > 0; off >>= 1)
        lsum += __shfl_xor(lsum, off, 64);
    if (lane == 0)
        atomicAdd(&accum[b & (NSLOTS - 1)], lsum);
}

__global__ void ssim_finalize(const float* __restrict__ accum,
                              float* __restrict__ out)
{
    const int l = threadIdx.x;  // 64 threads
    float s = accum[l] + accum[l + 64] + accum[l + 128] + accum[l + 192];
#pragma unroll
    for (int off = 32; off > 0; off >>= 1)
        s += __shfl_xor(s, off, 64);
    if (l == 0) out[0] = 1.0f - s / NPIXF;
}

extern "C" void kernel_launch(void* const* d_in, const int* in_sizes, int n_in,
                              void* d_out, int out_size, void* d_ws, size_t ws_size,
                              hipStream_t stream) {
    const float* pred = (const float*)d_in[0];
    const float* targ = (const float*)d_in[1];
    float* out = (float*)d_out;
    float* acc = (float*)d_ws;

    hipMemsetAsync(acc, 0, NSLOTS * sizeof(float), stream);
    ssim_band_kernel<<<NPLANES * NBANDS, 64, 0, stream>>>(pred, targ, acc);
    ssim_finalize<<<1, 64, 0, stream>>>(acc, out);
}